// Round 8
// baseline (1069.423 us; speedup 1.0000x reference)
//
#include <hip/hip_runtime.h>
#include <hip/hip_bf16.h>
#include <math.h>

#define BB 64
#define TT 256
#define CC 256
#define VV 65
#define LL 6
#define HH 8
#define BT (BB*TT)   // 16384

typedef unsigned short u16;
typedef __attribute__((ext_vector_type(8))) _Float16 h8v;   // 8 fp16 (4 VGPRs)
typedef __attribute__((ext_vector_type(4))) float f4v;      // MFMA acc
typedef __attribute__((ext_vector_type(4))) unsigned short u16x4;

typedef const unsigned int __attribute__((address_space(1))) gu32;
typedef unsigned int       __attribute__((address_space(3))) lu32;

__device__ inline u16 f2h(float f) { _Float16 h = (_Float16)f; return *(u16*)&h; }

__device__ inline void gld_lds16(const void* g, void* l) {
    __builtin_amdgcn_global_load_lds((gu32*)g, (lu32*)l, 16, 0, 0);
}

// Tiled operand format: matrix [R, K] -> tiles [R/128][K/64]; tile = 16384 B
// fp16, swizzled: element (r,k) at ushort index r*64 + ((k>>3)^(r&7))*8 + (k&7).

// ---------------- one-shot pack of ALL weights ----------------
__device__ inline void pack_dev(const float* __restrict__ src, u16* __restrict__ dst,
                                int K, int N, int NT, int KT, int id) {
    int perLayer = NT * KT * 8192;
    int l = id / perLayer; int rem = id - l * perLayer;
    int tile = rem >> 13, within = rem & 8191;
    int nT = tile / KT, kT = tile - nT * KT;
    int colIn = within >> 6, u = within & 63;
    int s = (u >> 3) ^ (colIn & 7);
    int k = kT * 64 + s * 8 + (u & 7);
    int n = nT * 128 + colIn;
    float v = (n < N) ? src[((size_t)l * K + k) * N + n] : 0.f;
    dst[((size_t)l * NT * KT + tile) * 8192 + within] = f2h(v);
}

#define E_QKV (LL*24*8192)      // 1,179,648
#define E_WO  (LL*8*8192)       //   393,216
#define E_W1  (LL*32*8192)      // 1,572,864
#define E_W2  (LL*32*8192)      // 1,572,864
#define E_LM  (4*8192)          //    32,768
#define E_QB  (LL*768)          //     4,608
#define E_TOT (E_QKV+E_WO+E_W1+E_W2+E_LM+E_QB)   // 4,755,968 = 256*18578

__global__ __launch_bounds__(256)
void pack_all(const float* __restrict__ wq, const float* __restrict__ wk,
              const float* __restrict__ wv, const float* __restrict__ wo,
              const float* __restrict__ w1, const float* __restrict__ w2,
              const float* __restrict__ lmw,
              const float* __restrict__ bq, const float* __restrict__ bk,
              const float* __restrict__ bv,
              u16* __restrict__ qkvT, u16* __restrict__ woT, u16* __restrict__ w1T,
              u16* __restrict__ w2T, u16* __restrict__ lmT, float* __restrict__ Bp) {
    int id = blockIdx.x * 256 + threadIdx.x;
    if (id < E_QKV) {
        // qkv: packed [K=256][N=768] from wq/wk/wv [L][H][C][32]
        const int perLayer = 24 * 8192;
        int l = id / perLayer; int rem = id - l * perLayer;
        int tile = rem >> 13, within = rem & 8191;
        int nT = tile >> 2, kT = tile & 3;
        int colIn = within >> 6, u = within & 63;
        int s = (u >> 3) ^ (colIn & 7);
        int k = kT * 64 + s * 8 + (u & 7);
        int n = nT * 128 + colIn;
        int which = n >> 8, hd = n & 255, h = hd >> 5, d = hd & 31;
        const float* src = (which == 0) ? wq : (which == 1) ? wk : wv;
        float v = src[(((size_t)l * HH + h) * CC + k) * 32 + d];
        qkvT[((size_t)l * 24 + tile) * 8192 + within] = f2h(v);
        return;
    }
    id -= E_QKV;
    if (id < E_WO) { pack_dev(wo, woT, 256, 256, 2, 4, id); return; }
    id -= E_WO;
    if (id < E_W1) { pack_dev(w1, w1T, 256, 1024, 8, 4, id); return; }
    id -= E_W1;
    if (id < E_W2) { pack_dev(w2, w2T, 1024, 256, 2, 16, id); return; }
    id -= E_W2;
    if (id < E_LM) { pack_dev(lmw, lmT, 256, VV, 1, 4, id); return; }
    id -= E_LM;
    if (id < E_QB) {
        int l = id / 768, j = id % 768;
        int which = j >> 8, hd = j & 255, h = hd >> 5, d = hd & 31;
        const float* src = (which == 0) ? bq : (which == 1) ? bk : bv;
        Bp[id] = src[((size_t)l * HH + h) * 32 + d];
    }
}

// ---------------- embedding ----------------
__global__ __launch_bounds__(256)
void embed_kernel(const int* __restrict__ idx, const float* __restrict__ te,
                  const float* __restrict__ pe, float* __restrict__ x) {
    int i = blockIdx.x * blockDim.x + threadIdx.x;
    if (i >= BT * 64) return;
    int bt = i >> 6, c4 = i & 63;
    int tok = idx[bt];
    int t = bt & (TT - 1);
    float4 a = ((const float4*)te)[(size_t)tok * 64 + c4];
    float4 p = ((const float4*)pe)[(size_t)t * 64 + c4];
    float4 o; o.x = a.x + p.x; o.y = a.y + p.y; o.z = a.z + p.z; o.w = a.w + p.w;
    ((float4*)x)[i] = o;
}

// ---------------- fused LN + MFMA GEMM (K = 256 = full feature dim) ----------
// C[16384,N] = LN(x; g,b) @ W.  BM=64 BN=128, 256 thr (4 waves 2x2, wave tile 32x64).
// A: staged fp32 -> wave-local LN -> swizzled fp16 LDS (full K resident, 32 KB).
// B: tiled fp16 image, global_load_lds, double-buffered (2 x 16 KB).
// EPI 0: fp16 row-major out + bias | 2: bias+relu -> tiled fp16 | 3: N=65 fp32 out
template<int EPI>
__global__ __launch_bounds__(256)
void gemm_ln(const float* __restrict__ X, const float* __restrict__ gw,
             const float* __restrict__ bw, const u16* __restrict__ Bt,
             const float* __restrict__ bias, void* __restrict__ Co,
             u16* __restrict__ CoT, int NT, int KTout) {
    __shared__ __align__(16) char lds[65536];   // A 0..32K (4 kt x 8K); B dbuf 32K..64K
    int tid = threadIdx.x;
    int l = tid & 63, w = tid >> 6;
    int nwg = gridDim.x;
    int id = blockIdx.x;
    int cpx = nwg >> 3;                          // grids are %8==0
    id = (id & 7) * cpx + (id >> 3);             // XCD-contiguous chunks
    int mT = id / NT, nT = id - mT * NT;

    // ---- stage A rows + LN (wave w owns rows r: r%4==w; lane l holds float4 col l)
    {
        const float* Xb = X + (size_t)mT * 64 * CC;
        float4 gv = ((const float4*)gw)[l];
        float4 bv = ((const float4*)bw)[l];
        int k0 = l * 4;
        int ktl = k0 >> 6, kIn = k0 & 63;
        int slot = kIn >> 3, jj = (kIn & 7);     // jj = 0 or 4
        #pragma unroll
        for (int i = 0; i < 16; ++i) {
            int r = i * 4 + w;
            float4 v = ((const float4*)(Xb + (size_t)r * CC))[l];
            float s = v.x + v.y + v.z + v.w;
            #pragma unroll
            for (int m = 1; m < 64; m <<= 1) s += __shfl_xor(s, m, 64);
            float mu = s * (1.f / CC);
            float dx = v.x - mu, dy = v.y - mu, dz = v.z - mu, dw = v.w - mu;
            float vs = dx * dx + dy * dy + dz * dz + dw * dw;
            #pragma unroll
            for (int m = 1; m < 64; m <<= 1) vs += __shfl_xor(vs, m, 64);
            float rs = rsqrtf(vs * (1.f / CC) + 1e-5f);
            u16x4 hv;
            hv[0] = f2h(dx * rs * gv.x + bv.x);
            hv[1] = f2h(dy * rs * gv.y + bv.y);
            hv[2] = f2h(dz * rs * gv.z + bv.z);
            hv[3] = f2h(dw * rs * gv.w + bv.w);
            *(u16x4*)(lds + ktl * 8192 + r * 128 + ((slot ^ (r & 7)) << 4) + jj * 2) = hv;
        }
    }

    // ---- B staging macro (16 KB per k-tile) ----
    const char* Bbase = (const char*)(Bt + (size_t)nT * 4 * 8192);
    #define STAGEB(buf, kt) {                                            \
        char* lb = lds + 32768 + (buf) * 16384 + w * 4096;               \
        const char* gb = Bbase + (kt) * 16384 + w * 4096 + l * 16;       \
        _Pragma("unroll")                                                \
        for (int j = 0; j < 4; ++j) gld_lds16(gb + j * 1024, lb + j * 1024); }

    STAGEB(0, 0);
    __syncthreads();

    int wm = w >> 1, wn = w & 1;
    int lrow = l & 15, lg = l >> 4;
    f4v acc[2][4];
    #pragma unroll
    for (int i = 0; i < 2; ++i)
        #pragma unroll
        for (int j = 0; j < 4; ++j) acc[i][j] = (f4v)0.f;

    int cur = 0;
    for (int kt = 0; kt < 4; ++kt) {
        if (kt < 3) STAGEB(cur ^ 1, kt + 1);
        const char* lb0 = lds + 32768 + cur * 16384;
        #pragma unroll
        for (int kh = 0; kh < 2; ++kh) {
            h8v ah[2], bh[4];
            #pragma unroll
            for (int mi = 0; mi < 2; ++mi) {
                int rc = wm * 32 + mi * 16 + lrow;
                ah[mi] = *(const h8v*)(lds + kt * 8192 + rc * 128 + 16 * ((kh * 4 + lg) ^ (rc & 7)));
            }
            #pragma unroll
            for (int ni = 0; ni < 4; ++ni) {
                int rc = wn * 64 + ni * 16 + lrow;
                bh[ni] = *(const h8v*)(lb0 + rc * 128 + 16 * ((kh * 4 + lg) ^ (rc & 7)));
            }
            #pragma unroll
            for (int mi = 0; mi < 2; ++mi)
                #pragma unroll
                for (int ni = 0; ni < 4; ++ni)
                    acc[mi][ni] = __builtin_amdgcn_mfma_f32_16x16x32_f16(ah[mi], bh[ni], acc[mi][ni], 0, 0, 0);
        }
        __syncthreads();
        cur ^= 1;
    }
    #undef STAGEB

    // epilogue: C frag col = l&15, row = (l>>4)*4 + q
    int colbase = nT * 128 + wn * 64;
    if (EPI == 0) {          // fp16 row-major [16384][768] + bias
        u16* Ch = (u16*)Co;
        #pragma unroll
        for (int mi = 0; mi < 2; ++mi) {
            int r0 = mT * 64 + wm * 32 + mi * 16 + lg * 4;
            #pragma unroll
            for (int ni = 0; ni < 4; ++ni) {
                int cg = colbase + ni * 16 + lrow;
                float bv = bias[cg];
                #pragma unroll
                for (int q = 0; q < 4; ++q)
                    Ch[(size_t)(r0 + q) * 768 + cg] = f2h(acc[mi][ni][q] + bv);
            }
        }
    } else if (EPI == 2) {   // bias + relu -> tiled fp16
        #pragma unroll
        for (int mi = 0; mi < 2; ++mi) {
            int r0 = mT * 64 + wm * 32 + mi * 16 + lg * 4;
            #pragma unroll
            for (int ni = 0; ni < 4; ++ni) {
                int cg = colbase + ni * 16 + lrow;
                float bv = bias[cg];
                int kTo = cg >> 6, kIn = cg & 63;
                #pragma unroll
                for (int q = 0; q < 4; ++q) {
                    int R = r0 + q;
                    int rIn = R & 127;
                    size_t tbase = ((size_t)(R >> 7) * KTout + kTo) * 8192;
                    float f = fmaxf(acc[mi][ni][q] + bv, 0.f);
                    int ub = rIn * 64 + (((kIn >> 3) ^ (rIn & 7)) << 3) + (kIn & 7);
                    CoT[tbase + ub] = f2h(f);
                }
            }
        }
    } else {                 // EPI 3: lm head fp32 [16384][65]
        float* Cf = (float*)Co;
        #pragma unroll
        for (int mi = 0; mi < 2; ++mi) {
            int r0 = mT * 64 + wm * 32 + mi * 16 + lg * 4;
            #pragma unroll
            for (int ni = 0; ni < 4; ++ni) {
                int cg = colbase + ni * 16 + lrow;
                if (cg < VV) {
                    float bv = bias[cg];
                    #pragma unroll
                    for (int q = 0; q < 4; ++q)
                        Cf[(size_t)(r0 + q) * VV + cg] = acc[mi][ni][q] + bv;
                }
            }
        }
    }
}

// ---------------- MFMA GEMM on tiled fp16 A (proj / w2), split-K atomics -------
// BM=128 BN=128 BK=64, 4 waves, dbuf prefetch. EPI 4: atomicAdd into residual (+bias@chunk0)
__global__ __launch_bounds__(256)
void gemm_mfma4(const u16* __restrict__ At, const u16* __restrict__ Bt,
                const float* __restrict__ bias, float* __restrict__ Co,
                int KTfull, int KTc, int NT, int N) {
    __shared__ __align__(16) char lds[65536];   // 2 bufs x (A 16K + B 16K)
    int tid = threadIdx.x;
    int l = tid & 63, w = tid >> 6;
    int nwg = gridDim.x;
    int id = blockIdx.x;
    int cpx = nwg >> 3;
    id = (id & 7) * cpx + (id >> 3);
    int mT = id / NT, nT = id - mT * NT;
    int ktBase = blockIdx.y * KTc;

    const char* Abase = (const char*)(At + ((size_t)mT * KTfull + ktBase) * 8192);
    const char* Bbase = (const char*)(Bt + ((size_t)nT * KTfull + ktBase) * 8192);
    int wm = w >> 1, wn = w & 1;

    f4v acc[4][4];
    #pragma unroll
    for (int i = 0; i < 4; ++i)
        #pragma unroll
        for (int j = 0; j < 4; ++j) acc[i][j] = (f4v)0.f;

    int lrow = l & 15, lg = l >> 4;

    #define STAGE(buf, kt) {                                           \
        char* la = lds + (buf) * 32768 + w * 4096;                     \
        char* lb = lds + (buf) * 32768 + 16384 + w * 4096;             \
        const char* ga = Abase + (kt) * 16384 + w * 4096 + l * 16;     \
        const char* gb = Bbase + (kt) * 16384 + w * 4096 + l * 16;     \
        _Pragma("unroll")                                              \
        for (int j = 0; j < 4; ++j) {                                  \
            gld_lds16(ga + j * 1024, la + j * 1024);                   \
            gld_lds16(gb + j * 1024, lb + j * 1024);                   \
        } }

    STAGE(0, 0);
    __syncthreads();
    int cur = 0;
    for (int kt = 0; kt < KTc; ++kt) {
        if (kt + 1 < KTc) STAGE(cur ^ 1, kt + 1);
        const char* lb0 = lds + cur * 32768;
        #pragma unroll
        for (int kh = 0; kh < 2; ++kh) {
            h8v ah[4], bh[4];
            #pragma unroll
            for (int mi = 0; mi < 4; ++mi) {
                int rc = wm * 64 + mi * 16 + lrow;
                ah[mi] = *(const h8v*)(lb0 + rc * 128 + 16 * ((kh * 4 + lg) ^ (rc & 7)));
            }
            #pragma unroll
            for (int ni = 0; ni < 4; ++ni) {
                int rc = wn * 64 + ni * 16 + lrow;
                bh[ni] = *(const h8v*)(lb0 + 16384 + rc * 128 + 16 * ((kh * 4 + lg) ^ (rc & 7)));
            }
            #pragma unroll
            for (int mi = 0; mi < 4; ++mi)
                #pragma unroll
                for (int ni = 0; ni < 4; ++ni)
                    acc[mi][ni] = __builtin_amdgcn_mfma_f32_16x16x32_f16(ah[mi], bh[ni], acc[mi][ni], 0, 0, 0);
        }
        __syncthreads();
        cur ^= 1;
    }
    #undef STAGE

    int colbase = nT * 128 + wn * 64;
    #pragma unroll
    for (int mi = 0; mi < 4; ++mi) {
        int r0 = mT * 128 + wm * 64 + mi * 16 + lg * 4;
        #pragma unroll
        for (int ni = 0; ni < 4; ++ni) {
            int cg = colbase + ni * 16 + lrow;
            float bv = (ktBase == 0) ? bias[cg] : 0.f;
            #pragma unroll
            for (int q = 0; q < 4; ++q)
                atomicAdd(Co + (size_t)(r0 + q) * N + cg, acc[mi][ni][q] + bv);
        }
    }
}

// ---------------- MFMA flash attention: block per (b,h), 4 waves ----------------
// qkv input fp16 row-major [16384][768].
// LDS: K fp16 [256][80B] @0 ; V^T fp16 [32][528B] @20480 ; P/wave [16][80B] @37376+w*1280.
__global__ __launch_bounds__(256)
void attn_mfma(const u16* __restrict__ qkv, u16* __restrict__ outT) {
    __shared__ __align__(16) char lds[42496];
    int bh = blockIdx.x;
    bh = (bh & 7) * 64 + (bh >> 3);      // bijective XCD swizzle (512 = 8*64)
    int b = bh >> 3, h = bh & 7;
    const u16* base = qkv + (size_t)b * TT * 768;
    int tid = threadIdx.x;
    int w = tid >> 6, l = tid & 63;
    int li = l & 15, g = l >> 4;

    {
        int r0 = tid >> 3, c = tid & 7;
        #pragma unroll
        for (int it = 0; it < 8; ++it) {
            int t = it * 32 + r0;
            u16x4 kv = *(const u16x4*)(base + (size_t)t * 768 + 256 + h * 32 + c * 4);
            u16x4 vv = *(const u16x4*)(base + (size_t)t * 768 + 512 + h * 32 + c * 4);
            *(u16x4*)(lds + t * 80 + c * 8) = kv;
            *(u16*)(lds + 20480 + (c * 4 + 0) * 528 + t * 2) = vv[0];
            *(u16*)(lds + 20480 + (c * 4 + 1) * 528 + t * 2) = vv[1];
            *(u16*)(lds + 20480 + (c * 4 + 2) * 528 + t * 2) = vv[2];
            *(u16*)(lds + 20480 + (c * 4 + 3) * 528 + t * 2) = vv[3];
        }
    }
    __syncthreads();

    char* Pb = lds + 37376 + w * 1280;
    int mts[4] = {w, 7 - w, 8 + w, 15 - w};
    #pragma unroll
    for (int im = 0; im < 4; ++im) {
        int mt = mts[im];
        int mq = mt * 16;
        h8v aq = *(const h8v*)(base + (size_t)(mq + li) * 768 + h * 32 + g * 8);

        f4v o0 = (f4v)0.f, o1 = (f4v)0.f;
        float mrun0 = -1e30f, mrun1 = -1e30f, mrun2 = -1e30f, mrun3 = -1e30f;
        float lrun0 = 0.f, lrun1 = 0.f, lrun2 = 0.f, lrun3 = 0.f;
        int nu = (mt >> 1) + 1;
        for (int kt = 0; kt < nu; ++kt) {
            int kb = kt * 32;
            h8v kf0 = *(const h8v*)(lds + (kb + li) * 80 + g * 16);
            h8v kf1 = *(const h8v*)(lds + (kb + 16 + li) * 80 + g * 16);
            f4v s0 = __builtin_amdgcn_mfma_f32_16x16x32_f16(aq, kf0, (f4v)0.f, 0, 0, 0);
            f4v s1 = __builtin_amdgcn_mfma_f32_16x16x32_f16(aq, kf1, (f4v)0.f, 0, 0, 0);
            bool maskunit = (kt == nu - 1);
            float p0[4], p1[4];
            float* mr[4] = {&mrun0, &mrun1, &mrun2, &mrun3};
            float* lr[4] = {&lrun0, &lrun1, &lrun2, &lrun3};
            #pragma unroll
            for (int qq = 0; qq < 4; ++qq) {
                float v0 = s0[qq] * 0.0625f;     // scale = C^-0.5 = 1/16
                float v1 = s1[qq] * 0.0625f;
                if (maskunit) {
                    int qg = mq + g * 4 + qq;
                    if (kb + li > qg)      v0 = -1e30f;
                    if (kb + 16 + li > qg) v1 = -1e30f;
                }
                float tm = fmaxf(v0, v1);
                #pragma unroll
                for (int msk = 1; msk < 16; msk <<= 1)
                    tm = fmaxf(tm, __shfl_xor(tm, msk, 64));
                float mold = *mr[qq];
                float mnew = fmaxf(mold, tm);
                float corr = __expf(mold - mnew);
                float e0 = __expf(v0 - mnew);
                float e1 = __expf(v1 - mnew);
                float ts = e0 + e1;
                #pragma unroll
                for (int msk = 1; msk < 16; msk <<= 1)
                    ts += __shfl_xor(ts, msk, 64);
                *lr[qq] = *lr[qq] * corr + ts;
                *mr[qq] = mnew;
                o0[qq] *= corr; o1[qq] *= corr;
                p0[qq] = e0; p1[qq] = e1;
            }
            #pragma unroll
            for (int qq = 0; qq < 4; ++qq) {
                *(u16*)(Pb + (g * 4 + qq) * 80 + li * 2)        = f2h(p0[qq]);
                *(u16*)(Pb + (g * 4 + qq) * 80 + (16 + li) * 2) = f2h(p1[qq]);
            }
            h8v pf  = *(const h8v*)(Pb + li * 80 + g * 16);
            h8v vf0 = *(const h8v*)(lds + 20480 + li * 528        + kb * 2 + g * 16);
            h8v vf1 = *(const h8v*)(lds + 20480 + (16 + li) * 528 + kb * 2 + g * 16);
            o0 = __builtin_amdgcn_mfma_f32_16x16x32_f16(pf, vf0, o0, 0, 0, 0);
            o1 = __builtin_amdgcn_mfma_f32_16x16x32_f16(pf, vf1, o1, 0, 0, 0);
        }
        float invs[4] = {1.f / lrun0, 1.f / lrun1, 1.f / lrun2, 1.f / lrun3};
        #pragma unroll
        for (int qq = 0; qq < 4; ++qq) {
            int tok = mq + g * 4 + qq;
            int rIn = tok & 127;
            size_t tb = ((size_t)(b * 2 + (tok >> 7)) * 4 + (h >> 1)) * 8192;
            float f0 = o0[qq] * invs[qq];
            float f1 = o1[qq] * invs[qq];
            int kIn0 = (h & 1) * 32 + li;
            int kIn1 = kIn0 + 16;
            int ub0 = rIn * 64 + (((kIn0 >> 3) ^ (rIn & 7)) << 3) + (kIn0 & 7);
            int ub1 = rIn * 64 + (((kIn1 >> 3) ^ (rIn & 7)) << 3) + (kIn1 & 7);
            outT[tb + ub0] = f2h(f0);
            outT[tb + ub1] = f2h(f1);
        }
    }
}

// ---------------- loss ----------------
__global__ __launch_bounds__(256)
void loss_kernel(const float* __restrict__ lg, const int* __restrict__ tgt,
                 float* __restrict__ loss) {
    int row = blockIdx.x * 256 + threadIdx.x;
    const float* r = lg + (size_t)row * VV;
    float mx = -INFINITY;
    for (int v = 0; v < VV; ++v) mx = fmaxf(mx, r[v]);
    float se = 0.f;
    for (int v = 0; v < VV; ++v) se += __expf(r[v] - mx);
    float nl = mx + __logf(se) - r[tgt[row]];
    #pragma unroll
    for (int m = 1; m < 64; m <<= 1) nl += __shfl_xor(nl, m, 64);
    __shared__ float wsum[4];
    int lane = threadIdx.x & 63, wv = threadIdx.x >> 6;
    if (lane == 0) wsum[wv] = nl;
    __syncthreads();
    if (threadIdx.x == 0)
        atomicAdd(loss, (wsum[0] + wsum[1] + wsum[2] + wsum[3]) * (1.f / BT));
}

extern "C" void kernel_launch(void* const* d_in, const int* in_sizes, int n_in,
                              void* d_out, int out_size, void* d_ws, size_t ws_size,
                              hipStream_t stream) {
    const int*   idx  = (const int*)d_in[0];
    const int*   tgt  = (const int*)d_in[1];
    const float* te   = (const float*)d_in[2];
    const float* pe   = (const float*)d_in[3];
    const float* wq   = (const float*)d_in[4];
    const float* bq   = (const float*)d_in[5];
    const float* wk   = (const float*)d_in[6];
    const float* bk   = (const float*)d_in[7];
    const float* wv   = (const float*)d_in[8];
    const float* bv   = (const float*)d_in[9];
    const float* wo   = (const float*)d_in[10];
    const float* bo   = (const float*)d_in[11];
    const float* ln1g = (const float*)d_in[12];
    const float* ln1b = (const float*)d_in[13];
    const float* w1   = (const float*)d_in[14];
    const float* b1   = (const float*)d_in[15];
    const float* w2   = (const float*)d_in[16];
    const float* b2   = (const float*)d_in[17];
    const float* ln2g = (const float*)d_in[18];
    const float* ln2b = (const float*)d_in[19];
    const float* lnfg = (const float*)d_in[20];
    const float* lnfb = (const float*)d_in[21];
    const float* lmw  = (const float*)d_in[22];
    const float* lmb  = (const float*)d_in[23];
    float* out = (float*)d_out;

    // workspace layout (bytes)
    char* base = (char*)d_ws;
    float* x       = (float*)(base);                       // 16 MB fp32 residual
    u16*   qkvh    = (u16*)  (base + (16ll << 20));        // 24 MB fp16 [16384][768]
    u16*   hiddenT = (u16*)  (base + (40ll << 20));        // 32 MB fp16 tiled
    u16*   xnT     = (u16*)  (base + (72ll << 20));        //  8 MB fp16 tiled (attn out)
    u16*   qkvT    = (u16*)  (base + (80ll << 20));        //  2.25 MB
    u16*   woT     = (u16*)  (base + (83ll << 20));        //  0.75 MB
    u16*   w1T     = (u16*)  (base + (84ll << 20));        //  3 MB
    u16*   w2T     = (u16*)  (base + (87ll << 20));        //  3 MB
    u16*   lmT     = (u16*)  (base + (90ll << 20));        //  64 KB
    float* Bp      = (float*)(base + (91ll << 20));        //  18 KB

    pack_all<<<dim3(E_TOT / 256), 256, 0, stream>>>(wq, wk, wv, wo, w1, w2, lmw,
                                                    bq, bk, bv,
                                                    qkvT, woT, w1T, w2T, lmT, Bp);
    embed_kernel<<<dim3((BT * 64) / 256), 256, 0, stream>>>(idx, te, pe, x);

    for (int l = 0; l < LL; ++l) {
        gemm_ln<0><<<dim3(256 * 6), 256, 0, stream>>>(
            x, ln1g + l * CC, ln1b + l * CC, qkvT + (size_t)l * 196608,
            Bp + l * 768, qkvh, nullptr, 6, 0);
        attn_mfma<<<dim3(BB * HH), 256, 0, stream>>>(qkvh, xnT);
        gemm_mfma4<<<dim3(128 * 2, 2), 256, 0, stream>>>(
            xnT, woT + (size_t)l * 65536, bo + l * CC, x, 4, 2, 2, 256);
        gemm_ln<2><<<dim3(256 * 8), 256, 0, stream>>>(
            x, ln2g + l * CC, ln2b + l * CC, w1T + (size_t)l * 262144,
            b1 + l * 1024, nullptr, hiddenT, 8, 16);
        gemm_mfma4<<<dim3(128 * 2, 2), 256, 0, stream>>>(
            hiddenT, w2T + (size_t)l * 262144, b2 + l * CC, x, 16, 8, 2, 256);
    }
    gemm_ln<3><<<dim3(256 * 1), 256, 0, stream>>>(
        x, lnfg, lnfb, lmT, lmb, out, nullptr, 1, 0);

    hipMemsetAsync(out + (size_t)BT * VV, 0, sizeof(float), stream);
    loss_kernel<<<dim3(BT / 256), 256, 0, stream>>>(out, tgt, out + (size_t)BT * VV);
}

// Round 10
// 980.444 us; speedup vs baseline: 1.0908x; 1.0908x over previous
//
#include <hip/hip_runtime.h>
#include <hip/hip_bf16.h>
#include <math.h>

#define BB 64
#define TT 256
#define CC 256
#define VV 65
#define LL 6
#define HH 8
#define BT (BB*TT)   // 16384

typedef unsigned short u16;
typedef __attribute__((ext_vector_type(8))) _Float16 h8v;   // 8 fp16 (4 VGPRs)
typedef __attribute__((ext_vector_type(4))) float f4v;      // MFMA acc
typedef __attribute__((ext_vector_type(4))) unsigned short u16x4;

typedef const unsigned int __attribute__((address_space(1))) gu32;
typedef unsigned int       __attribute__((address_space(3))) lu32;

__device__ inline u16 f2h(float f) { _Float16 h = (_Float16)f; return *(u16*)&h; }

__device__ inline void gld_lds16(const void* g, void* l) {
    __builtin_amdgcn_global_load_lds((gu32*)g, (lu32*)l, 16, 0, 0);
}

// Tiled operand format: matrix [R, K] -> tiles [R/128][K/64]; tile = 16384 B
// fp16, swizzled: element (r,k) at ushort index r*64 + ((k>>3)^(r&7))*8 + (k&7).

// ---------------- one-shot pack of ALL weights ----------------
__device__ inline void pack_dev(const float* __restrict__ src, u16* __restrict__ dst,
                                int K, int N, int NT, int KT, int id) {
    int perLayer = NT * KT * 8192;
    int l = id / perLayer; int rem = id - l * perLayer;
    int tile = rem >> 13, within = rem & 8191;
    int nT = tile / KT, kT = tile - nT * KT;
    int colIn = within >> 6, u = within & 63;
    int s = (u >> 3) ^ (colIn & 7);
    int k = kT * 64 + s * 8 + (u & 7);
    int n = nT * 128 + colIn;
    float v = (n < N) ? src[((size_t)l * K + k) * N + n] : 0.f;
    dst[((size_t)l * NT * KT + tile) * 8192 + within] = f2h(v);
}

#define E_QKV (LL*24*8192)
#define E_WO  (LL*8*8192)
#define E_W1  (LL*32*8192)
#define E_W2  (LL*32*8192)
#define E_LM  (4*8192)
#define E_QB  (LL*768)
#define E_TOT (E_QKV+E_WO+E_W1+E_W2+E_LM+E_QB)   // 4,755,968 = 256*18578

__global__ __launch_bounds__(256)
void pack_all(const float* __restrict__ wq, const float* __restrict__ wk,
              const float* __restrict__ wv, const float* __restrict__ wo,
              const float* __restrict__ w1, const float* __restrict__ w2,
              const float* __restrict__ lmw,
              const float* __restrict__ bq, const float* __restrict__ bk,
              const float* __restrict__ bv,
              u16* __restrict__ qkvT, u16* __restrict__ woT, u16* __restrict__ w1T,
              u16* __restrict__ w2T, u16* __restrict__ lmT, float* __restrict__ Bp) {
    int id = blockIdx.x * 256 + threadIdx.x;
    if (id < E_QKV) {
        const int perLayer = 24 * 8192;
        int l = id / perLayer; int rem = id - l * perLayer;
        int tile = rem >> 13, within = rem & 8191;
        int nT = tile >> 2, kT = tile & 3;
        int colIn = within >> 6, u = within & 63;
        int s = (u >> 3) ^ (colIn & 7);
        int k = kT * 64 + s * 8 + (u & 7);
        int n = nT * 128 + colIn;
        int which = n >> 8, hd = n & 255, h = hd >> 5, d = hd & 31;
        const float* src = (which == 0) ? wq : (which == 1) ? wk : wv;
        float v = src[(((size_t)l * HH + h) * CC + k) * 32 + d];
        qkvT[((size_t)l * 24 + tile) * 8192 + within] = f2h(v);
        return;
    }
    id -= E_QKV;
    if (id < E_WO) { pack_dev(wo, woT, 256, 256, 2, 4, id); return; }
    id -= E_WO;
    if (id < E_W1) { pack_dev(w1, w1T, 256, 1024, 8, 4, id); return; }
    id -= E_W1;
    if (id < E_W2) { pack_dev(w2, w2T, 1024, 256, 2, 16, id); return; }
    id -= E_W2;
    if (id < E_LM) { pack_dev(lmw, lmT, 256, VV, 1, 4, id); return; }
    id -= E_LM;
    if (id < E_QB) {
        int l = id / 768, j = id % 768;
        int which = j >> 8, hd = j & 255, h = hd >> 5, d = hd & 31;
        const float* src = (which == 0) ? bq : (which == 1) ? bk : bv;
        Bp[id] = src[((size_t)l * HH + h) * 32 + d];
    }
}

// ---------------- embedding ----------------
__global__ __launch_bounds__(256)
void embed_kernel(const int* __restrict__ idx, const float* __restrict__ te,
                  const float* __restrict__ pe, float* __restrict__ x) {
    int i = blockIdx.x * blockDim.x + threadIdx.x;
    if (i >= BT * 64) return;
    int bt = i >> 6, c4 = i & 63;
    int tok = idx[bt];
    int t = bt & (TT - 1);
    float4 a = ((const float4*)te)[(size_t)tok * 64 + c4];
    float4 p = ((const float4*)pe)[(size_t)t * 64 + c4];
    float4 o; o.x = a.x + p.x; o.y = a.y + p.y; o.z = a.z + p.z; o.w = a.w + p.w;
    ((float4*)x)[i] = o;
}

// ---------------- layernorm -> tiled fp16 (one wave per row, row computed once) --
__global__ __launch_bounds__(256)
void ln_kernel(const float* __restrict__ x, const float* __restrict__ g,
               const float* __restrict__ b, u16* __restrict__ outT) {
    int lane = threadIdx.x & 63;
    int wave = threadIdx.x >> 6;
    int row = blockIdx.x * 4 + wave;
    float4 v = ((const float4*)(x + (size_t)row * CC))[lane];
    float s = v.x + v.y + v.z + v.w;
    #pragma unroll
    for (int m = 1; m < 64; m <<= 1) s += __shfl_xor(s, m, 64);
    float mu = s * (1.f / CC);
    float dx = v.x - mu, dy = v.y - mu, dz = v.z - mu, dw = v.w - mu;
    float vs = dx * dx + dy * dy + dz * dz + dw * dw;
    #pragma unroll
    for (int m = 1; m < 64; m <<= 1) vs += __shfl_xor(vs, m, 64);
    float rs = rsqrtf(vs * (1.f / CC) + 1e-5f);
    float4 gv = ((const float4*)g)[lane];
    float4 bv = ((const float4*)b)[lane];
    float o[4];
    o[0] = dx * rs * gv.x + bv.x;
    o[1] = dy * rs * gv.y + bv.y;
    o[2] = dz * rs * gv.z + bv.z;
    o[3] = dw * rs * gv.w + bv.w;
    int rIn = row & 127, mT = row >> 7;
    int kT = lane >> 4;
    int kIn = (lane * 4) & 63;
    int slot = kIn >> 3, j = kIn & 7;          // j = 0 or 4
    size_t base = ((size_t)mT * 4 + kT) * 8192;
    int ub = rIn * 64 + ((slot ^ (rIn & 7)) << 3) + j;
    u16x4 hv;
    #pragma unroll
    for (int q = 0; q < 4; ++q) hv[q] = f2h(o[q]);
    *(u16x4*)(outT + base + ub) = hv;
}

// ---------------- MFMA GEMM: C[16384,N] = A @ W (A,B tiled fp16) --------------
// BM=128 BN=128 BK=64, 512 thr = 8 waves (4x2, wave tile 32x64), dbuf prefetch.
// EPI 0: fp16 row-major + bias | 2: bias+relu -> tiled fp16 | 3: N=65 fp32 | 4: atomicAdd
template<int EPI>
__global__ __launch_bounds__(512, 4)
void gemm_mfma(const u16* __restrict__ At, const u16* __restrict__ Bt,
               const float* __restrict__ bias, float* __restrict__ Co,
               u16* __restrict__ CoT, int KTfull, int KTc, int NT, int N, int KTout) {
    __shared__ __align__(16) char lds[65536];   // 2 bufs x (A 16K + B 16K)
    int tid = threadIdx.x;
    int l = tid & 63, w = tid >> 6;             // 8 waves
    int nwg = gridDim.x;
    int id = blockIdx.x;
    int cpx = nwg >> 3;                          // all grids %8==0
    id = (id & 7) * cpx + (id >> 3);             // XCD-contiguous chunks
    int mT = id / NT, nT = id - mT * NT;
    int ktBase = blockIdx.y * KTc;

    const char* Abase = (const char*)(At + ((size_t)mT * KTfull + ktBase) * 8192);
    const char* Bbase = (const char*)(Bt + ((size_t)nT * KTfull + ktBase) * 8192);
    int wm = w >> 1, wn = w & 1;                 // wave tile: rows [wm*32,+32), cols [wn*64,+64)

    f4v acc[2][4];
    #pragma unroll
    for (int i = 0; i < 2; ++i)
        #pragma unroll
        for (int j = 0; j < 4; ++j) acc[i][j] = (f4v)0.f;

    int lrow = l & 15, lg = l >> 4;

    // stage k-tile: each of 8 waves covers 2KB of A and 2KB of B per buffer
    #define STAGE(buf, kt) {                                           \
        char* la = lds + (buf) * 32768 + w * 2048;                     \
        char* lb = lds + (buf) * 32768 + 16384 + w * 2048;             \
        const char* ga = Abase + (kt) * 16384 + w * 2048 + l * 16;     \
        const char* gb = Bbase + (kt) * 16384 + w * 2048 + l * 16;     \
        _Pragma("unroll")                                              \
        for (int j = 0; j < 2; ++j) {                                  \
            gld_lds16(ga + j * 1024, la + j * 1024);                   \
            gld_lds16(gb + j * 1024, lb + j * 1024);                   \
        } }

    STAGE(0, 0);
    __syncthreads();
    int cur = 0;
    for (int kt = 0; kt < KTc; ++kt) {
        if (kt + 1 < KTc) STAGE(cur ^ 1, kt + 1);   // prefetch overlaps compute
        const char* lb0 = lds + cur * 32768;
        #pragma unroll
        for (int kh = 0; kh < 2; ++kh) {
            h8v ah[2], bh[4];
            #pragma unroll
            for (int mi = 0; mi < 2; ++mi) {
                int rc = wm * 32 + mi * 16 + lrow;
                ah[mi] = *(const h8v*)(lb0 + rc * 128 + 16 * ((kh * 4 + lg) ^ (rc & 7)));
            }
            #pragma unroll
            for (int ni = 0; ni < 4; ++ni) {
                int rc = wn * 64 + ni * 16 + lrow;
                bh[ni] = *(const h8v*)(lb0 + 16384 + rc * 128 + 16 * ((kh * 4 + lg) ^ (rc & 7)));
            }
            #pragma unroll
            for (int mi = 0; mi < 2; ++mi)
                #pragma unroll
                for (int ni = 0; ni < 4; ++ni)
                    acc[mi][ni] = __builtin_amdgcn_mfma_f32_16x16x32_f16(ah[mi], bh[ni], acc[mi][ni], 0, 0, 0);
        }
        __syncthreads();
        cur ^= 1;
    }
    #undef STAGE

    // epilogue: C frag col = l&15, row = (l>>4)*4 + q  [m89-verified]
    int colbase = nT * 128 + wn * 64;
    if (EPI == 0) {          // fp16 row-major [16384][N] + bias
        #pragma unroll
        for (int mi = 0; mi < 2; ++mi) {
            int r0 = mT * 128 + wm * 32 + mi * 16 + lg * 4;
            #pragma unroll
            for (int ni = 0; ni < 4; ++ni) {
                int cg = colbase + ni * 16 + lrow;
                float bv = bias[cg];
                #pragma unroll
                for (int q = 0; q < 4; ++q)
                    CoT[(size_t)(r0 + q) * N + cg] = f2h(acc[mi][ni][q] + bv);
            }
        }
    } else if (EPI == 2) {   // bias + relu -> tiled fp16
        #pragma unroll
        for (int mi = 0; mi < 2; ++mi) {
            int r0 = mT * 128 + wm * 32 + mi * 16 + lg * 4;
            #pragma unroll
            for (int ni = 0; ni < 4; ++ni) {
                int cg = colbase + ni * 16 + lrow;
                float bv = bias[cg];
                int kTo = cg >> 6, kIn = cg & 63;
                size_t tbase = ((size_t)mT * KTout + kTo) * 8192;
                #pragma unroll
                for (int q = 0; q < 4; ++q) {
                    int rIn = (r0 + q) & 127;
                    float f = fmaxf(acc[mi][ni][q] + bv, 0.f);
                    int ub = rIn * 64 + (((kIn >> 3) ^ (rIn & 7)) << 3) + (kIn & 7);
                    CoT[tbase + ub] = f2h(f);
                }
            }
        }
    } else if (EPI == 3) {   // lm head fp32 [16384][65]
        #pragma unroll
        for (int mi = 0; mi < 2; ++mi) {
            int r0 = mT * 128 + wm * 32 + mi * 16 + lg * 4;
            #pragma unroll
            for (int ni = 0; ni < 4; ++ni) {
                int cg = colbase + ni * 16 + lrow;
                if (cg < VV) {
                    float bv = bias[cg];
                    #pragma unroll
                    for (int q = 0; q < 4; ++q)
                        Co[(size_t)(r0 + q) * VV + cg] = acc[mi][ni][q] + bv;
                }
            }
        }
    } else {                 // EPI 4: split-K atomic accumulate into residual
        #pragma unroll
        for (int mi = 0; mi < 2; ++mi) {
            int r0 = mT * 128 + wm * 32 + mi * 16 + lg * 4;
            #pragma unroll
            for (int ni = 0; ni < 4; ++ni) {
                int cg = colbase + ni * 16 + lrow;
                float bv = (ktBase == 0) ? bias[cg] : 0.f;
                #pragma unroll
                for (int q = 0; q < 4; ++q)
                    atomicAdd(Co + (size_t)(r0 + q) * N + cg, acc[mi][ni][q] + bv);
            }
        }
    }
}

// ---------------- MFMA flash attention: block per (b,h), 4 waves ----------------
// qkv input fp16 row-major [16384][768].
// LDS: K fp16 [256][80B] @0 ; V^T fp16 [32][528B] @20480 ; P/wave [16][80B] @37376+w*1280.
__global__ __launch_bounds__(256)
void attn_mfma(const u16* __restrict__ qkv, u16* __restrict__ outT) {
    __shared__ __align__(16) char lds[42496];
    int bh = blockIdx.x;
    bh = (bh & 7) * 64 + (bh >> 3);      // bijective XCD swizzle (512 = 8*64)
    int b = bh >> 3, h = bh & 7;
    const u16* base = qkv + (size_t)b * TT * 768;
    int tid = threadIdx.x;
    int w = tid >> 6, l = tid & 63;
    int li = l & 15, g = l >> 4;

    {
        int r0 = tid >> 3, c = tid & 7;
        #pragma unroll
        for (int it = 0; it < 8; ++it) {
            int t = it * 32 + r0;
            u16x4 kv = *(const u16x4*)(base + (size_t)t * 768 + 256 + h * 32 + c * 4);
            u16x4 vv = *(const u16x4*)(base + (size_t)t * 768 + 512 + h * 32 + c * 4);
            *(u16x4*)(lds + t * 80 + c * 8) = kv;
            *(u16*)(lds + 20480 + (c * 4 + 0) * 528 + t * 2) = vv[0];
            *(u16*)(lds + 20480 + (c * 4 + 1) * 528 + t * 2) = vv[1];
            *(u16*)(lds + 20480 + (c * 4 + 2) * 528 + t * 2) = vv[2];
            *(u16*)(lds + 20480 + (c * 4 + 3) * 528 + t * 2) = vv[3];
        }
    }
    __syncthreads();

    char* Pb = lds + 37376 + w * 1280;
    int mts[4] = {w, 7 - w, 8 + w, 15 - w};
    #pragma unroll
    for (int im = 0; im < 4; ++im) {
        int mt = mts[im];
        int mq = mt * 16;
        h8v aq = *(const h8v*)(base + (size_t)(mq + li) * 768 + h * 32 + g * 8);

        f4v o0 = (f4v)0.f, o1 = (f4v)0.f;
        float mrun0 = -1e30f, mrun1 = -1e30f, mrun2 = -1e30f, mrun3 = -1e30f;
        float lrun0 = 0.f, lrun1 = 0.f, lrun2 = 0.f, lrun3 = 0.f;
        int nu = (mt >> 1) + 1;
        for (int kt = 0; kt < nu; ++kt) {
            int kb = kt * 32;
            h8v kf0 = *(const h8v*)(lds + (kb + li) * 80 + g * 16);
            h8v kf1 = *(const h8v*)(lds + (kb + 16 + li) * 80 + g * 16);
            f4v s0 = __builtin_amdgcn_mfma_f32_16x16x32_f16(aq, kf0, (f4v)0.f, 0, 0, 0);
            f4v s1 = __builtin_amdgcn_mfma_f32_16x16x32_f16(aq, kf1, (f4v)0.f, 0, 0, 0);
            bool maskunit = (kt == nu - 1);
            float p0[4], p1[4];
            float* mr[4] = {&mrun0, &mrun1, &mrun2, &mrun3};
            float* lr[4] = {&lrun0, &lrun1, &lrun2, &lrun3};
            #pragma unroll
            for (int qq = 0; qq < 4; ++qq) {
                float v0 = s0[qq] * 0.0625f;     // scale = C^-0.5 = 1/16
                float v1 = s1[qq] * 0.0625f;
                if (maskunit) {
                    int qg = mq + g * 4 + qq;
                    if (kb + li > qg)      v0 = -1e30f;
                    if (kb + 16 + li > qg) v1 = -1e30f;
                }
                float tm = fmaxf(v0, v1);
                #pragma unroll
                for (int msk = 1; msk < 16; msk <<= 1)
                    tm = fmaxf(tm, __shfl_xor(tm, msk, 64));
                float mold = *mr[qq];
                float mnew = fmaxf(mold, tm);
                float corr = __expf(mold - mnew);
                float e0 = __expf(v0 - mnew);
                float e1 = __expf(v1 - mnew);
                float ts = e0 + e1;
                #pragma unroll
                for (int msk = 1; msk < 16; msk <<= 1)
                    ts += __shfl_xor(ts, msk, 64);
                *lr[qq] = *lr[qq] * corr + ts;
                *mr[qq] = mnew;
                o0[qq] *= corr; o1[qq] *= corr;
                p0[qq] = e0; p1[qq] = e1;
            }
            #pragma unroll
            for (int qq = 0; qq < 4; ++qq) {
                *(u16*)(Pb + (g * 4 + qq) * 80 + li * 2)        = f2h(p0[qq]);
                *(u16*)(Pb + (g * 4 + qq) * 80 + (16 + li) * 2) = f2h(p1[qq]);
            }
            h8v pf  = *(const h8v*)(Pb + li * 80 + g * 16);
            h8v vf0 = *(const h8v*)(lds + 20480 + li * 528        + kb * 2 + g * 16);
            h8v vf1 = *(const h8v*)(lds + 20480 + (16 + li) * 528 + kb * 2 + g * 16);
            o0 = __builtin_amdgcn_mfma_f32_16x16x32_f16(pf, vf0, o0, 0, 0, 0);
            o1 = __builtin_amdgcn_mfma_f32_16x16x32_f16(pf, vf1, o1, 0, 0, 0);
        }
        float invs[4] = {1.f / lrun0, 1.f / lrun1, 1.f / lrun2, 1.f / lrun3};
        #pragma unroll
        for (int qq = 0; qq < 4; ++qq) {
            int tok = mq + g * 4 + qq;
            int rIn = tok & 127;
            size_t tb = ((size_t)(b * 2 + (tok >> 7)) * 4 + (h >> 1)) * 8192;
            float f0 = o0[qq] * invs[qq];
            float f1 = o1[qq] * invs[qq];
            int kIn0 = (h & 1) * 32 + li;
            int kIn1 = kIn0 + 16;
            int ub0 = rIn * 64 + (((kIn0 >> 3) ^ (rIn & 7)) << 3) + (kIn0 & 7);
            int ub1 = rIn * 64 + (((kIn1 >> 3) ^ (rIn & 7)) << 3) + (kIn1 & 7);
            outT[tb + ub0] = f2h(f0);
            outT[tb + ub1] = f2h(f1);
        }
    }
}

// ---------------- loss ----------------
__global__ __launch_bounds__(256)
void loss_kernel(const float* __restrict__ lg, const int* __restrict__ tgt,
                 float* __restrict__ loss) {
    int row = blockIdx.x * 256 + threadIdx.x;
    const float* r = lg + (size_t)row * VV;
    float mx = -INFINITY;
    for (int v = 0; v < VV; ++v) mx = fmaxf(mx, r[v]);
    float se = 0.f;
    for (int v = 0; v < VV; ++v) se += __expf(r[v] - mx);
    float nl = mx + __logf(se) - r[tgt[row]];
    #pragma unroll
    for (int m = 1; m < 64; m <<= 1) nl += __shfl_xor(nl, m, 64);
    __shared__ float wsum[4];
    int lane = threadIdx.x & 63, wv = threadIdx.x >> 6;
    if (lane == 0) wsum[wv] = nl;
    __syncthreads();
    if (threadIdx.x == 0)
        atomicAdd(loss, (wsum[0] + wsum[1] + wsum[2] + wsum[3]) * (1.f / BT));
}

extern "C" void kernel_launch(void* const* d_in, const int* in_sizes, int n_in,
                              void* d_out, int out_size, void* d_ws, size_t ws_size,
                              hipStream_t stream) {
    const int*   idx  = (const int*)d_in[0];
    const int*   tgt  = (const int*)d_in[1];
    const float* te   = (const float*)d_in[2];
    const float* pe   = (const float*)d_in[3];
    const float* wq   = (const float*)d_in[4];
    const float* bq   = (const float*)d_in[5];
    const float* wk   = (const float*)d_in[6];
    const float* bk   = (const float*)d_in[7];
    const float* wv   = (const float*)d_in[8];
    const float* bv   = (const float*)d_in[9];
    const float* wo   = (const float*)d_in[10];
    const float* bo   = (const float*)d_in[11];
    const float* ln1g = (const float*)d_in[12];
    const float* ln1b = (const float*)d_in[13];
    const float* w1   = (const float*)d_in[14];
    const float* b1   = (const float*)d_in[15];
    const float* w2   = (const float*)d_in[16];
    const float* b2   = (const float*)d_in[17];
    const float* ln2g = (const float*)d_in[18];
    const float* ln2b = (const float*)d_in[19];
    const float* lnfg = (const float*)d_in[20];
    const float* lnfb = (const float*)d_in[21];
    const float* lmw  = (const float*)d_in[22];
    const float* lmb  = (const float*)d_in[23];
    float* out = (float*)d_out;

    // workspace layout (bytes)
    char* base = (char*)d_ws;
    float* x       = (float*)(base);                       // 16 MB fp32 residual
    u16*   qkvh    = (u16*)  (base + (16ll << 20));        // 24 MB fp16 [16384][768]
    u16*   hiddenT = (u16*)  (base + (40ll << 20));        // 32 MB fp16 tiled
    u16*   xnT     = (u16*)  (base + (72ll << 20));        //  8 MB fp16 tiled
    u16*   qkvT    = (u16*)  (base + (80ll << 20));        //  2.25 MB
    u16*   woT     = (u16*)  (base + (83ll << 20));        //  0.75 MB
    u16*   w1T     = (u16*)  (base + (84ll << 20));        //  3 MB
    u16*   w2T     = (u16*)  (base + (87ll << 20));        //  3 MB
    u16*   lmT     = (u16*)  (base + (90ll << 20));        //  64 KB
    float* Bp      = (float*)(base + (91ll << 20));        //  18 KB

    pack_all<<<dim3(E_TOT / 256), 256, 0, stream>>>(wq, wk, wv, wo, w1, w2, lmw,
                                                    bq, bk, bv,
                                                    qkvT, woT, w1T, w2T, lmT, Bp);
    embed_kernel<<<dim3((BT * 64) / 256), 256, 0, stream>>>(idx, te, pe, x);

    for (int l = 0; l < LL; ++l) {
        ln_kernel<<<dim3(BT / 4), 256, 0, stream>>>(x, ln1g + l * CC, ln1b + l * CC, xnT);
        gemm_mfma<0><<<dim3(128 * 6, 1), 512, 0, stream>>>(
            xnT, qkvT + (size_t)l * 196608, Bp + l * 768, nullptr, qkvh, 4, 4, 6, 768, 0);
        attn_mfma<<<dim3(BB * HH), 256, 0, stream>>>(qkvh, xnT);
        gemm_mfma<4><<<dim3(128 * 2, 2), 512, 0, stream>>>(
            xnT, woT + (size_t)l * 65536, bo + l * CC, x, nullptr, 4, 2, 2, 256, 0);
        ln_kernel<<<dim3(BT / 4), 256, 0, stream>>>(x, ln2g + l * CC, ln2b + l * CC, xnT);
        gemm_mfma<2><<<dim3(128 * 8, 1), 512, 0, stream>>>(
            xnT, w1T + (size_t)l * 262144, b1 + l * 1024, nullptr, hiddenT, 4, 4, 8, 1024, 16);
        gemm_mfma<4><<<dim3(128 * 2, 2), 512, 0, stream>>>(
            hiddenT, w2T + (size_t)l * 262144, b2 + l * CC, x, nullptr, 16, 8, 2, 256, 0);
    }
    ln_kernel<<<dim3(BT / 4), 256, 0, stream>>>(x, lnfg, lnfb, xnT);
    gemm_mfma<3><<<dim3(128 * 1, 1), 512, 0, stream>>>(
        xnT, lmT, lmb, out, nullptr, 4, 4, 1, VV, 0);

    hipMemsetAsync(out + (size_t)BT * VV, 0, sizeof(float), stream);
    loss_kernel<<<dim3(BT / 256), 256, 0, stream>>>(out, tgt, out + (size_t)BT * VV);
}